// Round 1
// baseline (339.113 us; speedup 1.0000x reference)
//
#include <hip/hip_runtime.h>
#include <stdint.h>

// PCLayer closed form: x = (t - b) @ A,  A = 0.01*W + lr*W@S',
// S' = -45E + 120E^2 - 210E^3 + 252E^4,  E = lr*W^T W   (||E||<=0.009)

typedef short bf16x8 __attribute__((ext_vector_type(8)));   // 8 bf16 = 4 VGPRs
typedef float f32x4  __attribute__((ext_vector_type(4)));
typedef unsigned short u16;
typedef unsigned int uint_as1 __attribute__((address_space(1)));
typedef unsigned int uint_as3 __attribute__((address_space(3)));

__device__ __forceinline__ float bf2f(u16 u) {
  union { unsigned int i; float f; } x; x.i = ((unsigned int)u) << 16; return x.f;
}
__device__ __forceinline__ u16 f2bf(float f) {  // round-to-nearest-even
  union { float f; unsigned int i; } x; x.f = f;
  unsigned int r = x.i + 0x7fffu + ((x.i >> 16) & 1u);
  return (u16)(r >> 16);
}
__device__ __forceinline__ void gl2lds16(const void* g, void* l) {
  // async 16B/lane global->LDS; LDS dst = wave-uniform base + lane*16
  __builtin_amdgcn_global_load_lds((uint_as1*)(uintptr_t)g,
                                   (uint_as3*)(uintptr_t)l, 16, 0, 0);
}

// C[M,N] = alpha * A[M,K] @ B[N,K]^T  (both bf16 row-major, lda=ldb=K)
// MODE 0: Cf = v (fp32 store)   MODE 1: atomicAdd(Cf, v)  (split-K over blockIdx.z)
// MODE 2: Cb = bf16(v + addScale*Add[idx])
template<int MODE>
__global__ __launch_bounds__(256, 2)
void gemm_bt(const u16* __restrict__ A, const u16* __restrict__ B,
             float* __restrict__ Cf, u16* __restrict__ Cb,
             const u16* __restrict__ Add,
             float alpha, float addScale, int K, int ldc, int kc)
{
  __shared__ u16 As[128 * 32];   // [m][k], 64B rows
  __shared__ u16 Bs[128 * 32];   // [n][k]
  const int tid  = threadIdx.x;
  const int w    = tid >> 6, lane = tid & 63;
  const int lm   = lane & 15, quad = lane >> 4;
  const int wm   = w & 1, wn = w >> 1;          // 2x2 wave grid, 64x64 each
  const int m0   = blockIdx.x * 128, n0 = blockIdx.y * 128;
  const long k0  = (long)blockIdx.z * kc;

  const u16* Ag = A + (long)(m0 + w * 32 + (lane >> 2)) * K + k0 + (lane & 3) * 8;
  const u16* Bg = B + (long)(n0 + w * 32 + (lane >> 2)) * K + k0 + (lane & 3) * 8;
  u16* Asl = As + w * 1024;   // wave stages rows [w*32, w*32+32)
  u16* Bsl = Bs + w * 1024;

  f32x4 acc[4][4] = {};

  for (int kk = 0; kk < kc; kk += 32) {
    gl2lds16(Ag + kk, Asl);
    gl2lds16(Ag + 16 * (long)K + kk, Asl + 512);
    gl2lds16(Bg + kk, Bsl);
    gl2lds16(Bg + 16 * (long)K + kk, Bsl + 512);
    __syncthreads();                       // drains vmcnt before barrier
    bf16x8 af[4], bv[4];
#pragma unroll
    for (int i = 0; i < 4; ++i) {
      af[i] = *(const bf16x8*)(As + (wm * 64 + i * 16 + lm) * 32 + quad * 8);
      bv[i] = *(const bf16x8*)(Bs + (wn * 64 + i * 16 + lm) * 32 + quad * 8);
    }
#pragma unroll
    for (int i = 0; i < 4; ++i)
#pragma unroll
      for (int j = 0; j < 4; ++j)
        acc[i][j] = __builtin_amdgcn_mfma_f32_16x16x32_bf16(af[i], bv[j], acc[i][j], 0, 0, 0);
    __syncthreads();
  }

  // C/D layout (m89-verified): col = lane&15, row = quad*4 + reg
  const int rbase = m0 + wm * 64 + quad * 4;
  const int cbase = n0 + wn * 64 + lm;
#pragma unroll
  for (int i = 0; i < 4; ++i)
#pragma unroll
    for (int j = 0; j < 4; ++j) {
      const int col = cbase + j * 16;
#pragma unroll
      for (int r = 0; r < 4; ++r) {
        const long idx = (long)(rbase + i * 16 + r) * ldc + col;
        float v = alpha * acc[i][j][r];
        if (MODE == 0) {
          Cf[idx] = v;
        } else if (MODE == 1) {
          atomicAdd(&Cf[idx], v);
        } else {
          v += addScale * bf2f(Add[idx]);
          Cb[idx] = f2bf(v);
        }
      }
    }
}

// t[8192,3072] fp32 -> bf16 (t - b), vectorized x4
__global__ void conv_t_kernel(const float* __restrict__ t, const float* __restrict__ bias,
                              u16* __restrict__ tb)
{
  const long i4 = (long)blockIdx.x * 256 + threadIdx.x;   // < 6291456
  const float4 v = ((const float4*)t)[i4];
  const int col4 = (int)(i4 % 768);                        // (i4*4 % 3072)/4
  const float4 bb = ((const float4*)bias)[col4];
  ushort4 o;
  o.x = f2bf(v.x - bb.x); o.y = f2bf(v.y - bb.y);
  o.z = f2bf(v.z - bb.z); o.w = f2bf(v.w - bb.w);
  ((ushort4*)tb)[i4] = o;
}

// W[3072,768] fp32 -> Wb bf16 (same layout) + WTb bf16 [768,3072] (transposed)
__global__ void conv_w_kernel(const float* __restrict__ W, u16* __restrict__ Wb,
                              u16* __restrict__ WTb)
{
  const int i = blockIdx.x * 256 + threadIdx.x;   // < 2359296
  const float v = W[i];
  const u16 u = f2bf(v);
  Wb[i] = u;
  const int o = i / 768, c = i - o * 768;
  WTb[(long)c * 3072 + o] = u;                     // scattered 2B; L2 absorbs (4.7MB)
}

// dstb = bf16(src) (if dstb); acc = init ? coef*src : acc + coef*src (if acc)
__global__ void conv_acc_kernel(const float* __restrict__ src, u16* __restrict__ dstb,
                                float* __restrict__ acc, float coef, int init)
{
  const int i = blockIdx.x * 256 + threadIdx.x;   // < 589824
  const float s = src[i];
  if (dstb) dstb[i] = f2bf(s);
  if (acc)  acc[i] = init ? (coef * s) : fmaf(coef, s, acc[i]);
}

extern "C" void kernel_launch(void* const* d_in, const int* in_sizes, int n_in,
                              void* d_out, int out_size, void* d_ws, size_t ws_size,
                              hipStream_t stream)
{
  const float* t    = (const float*)d_in[0];   // [8,1024,3072]
  const float* W    = (const float*)d_in[1];   // [3072,768]
  const float* bias = (const float*)d_in[2];   // [3072] (zeros, handled anyway)
  float* out = (float*)d_out;                  // [8192,768] fp32

  char* p = (char*)d_ws;                       // total 79,822,848 B
  u16*   tb  = (u16*)(p + 0);                  // 50,331,648  bf16 t-b [8192,3072]
  u16*   Wb  = (u16*)(p + 50331648);           //  4,718,592  bf16 W  [3072,768]
  u16*   WTb = (u16*)(p + 55050240);           //  4,718,592  bf16 W^T [768,3072]
  u16*   Amb = (u16*)(p + 59768832);           //  4,718,592  bf16 A^T [768,3072]
  float* Ef  = (float*)(p + 64487424);         //  2,359,296  E fp32 [768,768]
  float* P2f = (float*)(p + 66846720);         //  2,359,296  E^2
  float* P3f = (float*)(p + 69206016);         //  2,359,296  E^3
  float* P4f = (float*)(p + 71565312);         //  2,359,296  E^4
  float* Sac = (float*)(p + 73924608);         //  2,359,296  S' accumulator
  u16*   Eb  = (u16*)(p + 76283904);           //  1,179,648  bf16 E
  u16*   P2b = (u16*)(p + 77463552);           //  1,179,648  bf16 E^2
  u16*   Spb = (u16*)(p + 78643200);           //  1,179,648  bf16 S'

  const float lr = 0.001f;

  hipMemsetAsync(Ef, 0, 4 * 2359296, stream);  // zero atomicAdd targets Ef..P4f
  conv_t_kernel<<<24576, 256, 0, stream>>>(t, bias, tb);
  conv_w_kernel<<<9216, 256, 0, stream>>>(W, Wb, WTb);

  // E = lr * W^T W : BT-GEMM with A=B=WT [768,3072], split-K x8
  gemm_bt<1><<<dim3(6, 6, 8), 256, 0, stream>>>(WTb, WTb, Ef, nullptr, nullptr,
                                                lr, 0.f, 3072, 768, 384);
  conv_acc_kernel<<<2304, 256, 0, stream>>>(Ef, Eb, Sac, -45.f, 1);
  // E^2 = E E^T (E symmetric), split-K x4
  gemm_bt<1><<<dim3(6, 6, 4), 256, 0, stream>>>(Eb, Eb, P2f, nullptr, nullptr,
                                                1.f, 0.f, 768, 768, 192);
  conv_acc_kernel<<<2304, 256, 0, stream>>>(P2f, P2b, Sac, 120.f, 0);
  // E^3 = E^2 E^T
  gemm_bt<1><<<dim3(6, 6, 4), 256, 0, stream>>>(P2b, Eb, P3f, nullptr, nullptr,
                                                1.f, 0.f, 768, 768, 192);
  conv_acc_kernel<<<2304, 256, 0, stream>>>(P3f, nullptr, Sac, -210.f, 0);
  // E^4 = E^2 (E^2)^T
  gemm_bt<1><<<dim3(6, 6, 4), 256, 0, stream>>>(P2b, P2b, P4f, nullptr, nullptr,
                                                1.f, 0.f, 768, 768, 192);
  conv_acc_kernel<<<2304, 256, 0, stream>>>(P4f, nullptr, Sac, 252.f, 0);
  conv_acc_kernel<<<2304, 256, 0, stream>>>(Sac, Spb, nullptr, 0.f, 0);

  // A^T[i,o] = lr * (S' @ W^T)[i,o] + 0.01*W^T[i,o]  (S' symmetric)
  // BT-GEMM: A=S'[768,768], B=Wb[3072,768], M=768,N=3072,K=768
  gemm_bt<2><<<dim3(6, 24, 1), 256, 0, stream>>>(Spb, Wb, nullptr, Amb, WTb,
                                                 lr, 0.01f, 768, 3072, 768);
  // x = (t-b) @ A : A=tb[8192,3072], B=A^T[768,3072], M=8192,N=768,K=3072
  gemm_bt<0><<<dim3(64, 6, 1), 256, 0, stream>>>(tb, Amb, out, nullptr, nullptr,
                                                 1.f, 0.f, 3072, 768, 3072);
}